// Round 1
// baseline (60.794 us; speedup 1.0000x reference)
//
#include <hip/hip_runtime.h>
#include <stdint.h>

#define PW 3
#define S 9          // PW*PW
#define LSZ 64       // GRID*GRID sites
#define NP 64        // plaquettes
#define M 128
#define BATCH 2048
#define NPAT 512     // 2^9 occupation patterns

// ---------------------------------------------------------------------------
// Kernel 1: G[p][pat] = sum_m prod_s eps[bit_s(pat)][p][m][s]
// Split pattern bits 5/4:  A[lo][m] = prod_{s=0..4}, B[hi][m] = prod_{s=5..8}
// grid = NP*4 blocks: block = (p, quadrant q of hi), 128 threads.
// Thread t acts as m=t in the build phase, as pattern (lo,hl) in the G phase.
// ---------------------------------------------------------------------------
__global__ __launch_bounds__(128) void build_table(
    const float* __restrict__ eps,   // [2][NP][M][S]
    float* __restrict__ G)           // [NP][NPAT]
{
    const int p = blockIdx.x >> 2;
    const int q = blockIdx.x & 3;    // hi = q*4 + hl, hl in 0..3
    const int t = threadIdx.x;       // 0..127

    // +4 pad: row stride 132 words -> float4-aligned rows, banks (4*lo+m)%32
    __shared__ float As[32][M + 4];
    __shared__ float Bs[4][M + 4];

    // ---- build phase: thread t == m ----
    const int m = t;
    const float* ep = eps + (size_t)p * (M * S) + (size_t)m * S;
    const int dstride = NP * M * S;  // 73728

    float e0[S], e1[S];
#pragma unroll
    for (int s = 0; s < S; ++s) {
        e0[s] = ep[s];
        e1[s] = ep[dstride + s];
    }
    // sub-products for bits 0..1 and 2..4
    float c01[4], c234[8];
#pragma unroll
    for (int i = 0; i < 4; ++i)
        c01[i] = ((i & 1) ? e1[0] : e0[0]) * ((i & 2) ? e1[1] : e0[1]);
#pragma unroll
    for (int i = 0; i < 8; ++i)
        c234[i] = ((i & 1) ? e1[2] : e0[2]) * ((i & 2) ? e1[3] : e0[3]) *
                  ((i & 4) ? e1[4] : e0[4]);
#pragma unroll
    for (int lo = 0; lo < 32; ++lo)
        As[lo][m] = c01[lo & 3] * c234[lo >> 2];

    // hi bits: s5 = hi&1, s6 = (hi>>1)&1, s7 = (hi>>2)&1, s8 = (hi>>3)&1
    const float tail = ((q & 1) ? e1[7] : e0[7]) * ((q & 2) ? e1[8] : e0[8]);
#pragma unroll
    for (int hl = 0; hl < 4; ++hl)
        Bs[hl][m] = ((hl & 1) ? e1[5] : e0[5]) * ((hl & 2) ? e1[6] : e0[6]) * tail;

    __syncthreads();

    // ---- G phase: thread = pattern (lo = t&31, hl = t>>5) ----
    const int lo = t & 31;
    const int hl = t >> 5;
    const float4* Arow = (const float4*)&As[lo][0];
    const float4* Brow = (const float4*)&Bs[hl][0];
    float acc = 0.f;
#pragma unroll 8
    for (int i = 0; i < M / 4; ++i) {
        float4 a = Arow[i];
        float4 b = Brow[i];
        acc += a.x * b.x + a.y * b.y + a.z * b.z + a.w * b.w;
    }
    const int hi = q * 4 + hl;
    G[p * NPAT + (hi << 5) + lo] = acc;
}

// ---------------------------------------------------------------------------
// Kernel 2: one wave per batch element. Lane l loads site l (L=64=wave),
// ballot -> 64-bit occupation mask, lane p extracts its 9-bit pattern,
// one table lookup, shuffle-reduce over the 64 plaquettes.
// ---------------------------------------------------------------------------
__global__ __launch_bounds__(256) void eval_kernel(
    const int* __restrict__ inputs,   // [BATCH][LSZ]
    const int* __restrict__ plq,      // [NP][S]
    const float* __restrict__ G,      // [NP][NPAT]
    float* __restrict__ out)          // [BATCH]
{
    __shared__ int splq[NP * S];
    for (int i = threadIdx.x; i < NP * S; i += 256)
        splq[i] = plq[i];
    __syncthreads();

    const int wave = threadIdx.x >> 6;
    const int lane = threadIdx.x & 63;
    const int b = blockIdx.x * 4 + wave;

    const int v = inputs[b * LSZ + lane];
    const unsigned long long mask = __ballot(v != 0);

    // lane doubles as plaquette index p
    int pat = 0;
#pragma unroll
    for (int s = 0; s < S; ++s) {
        const int site = splq[lane * S + s];
        pat |= (int)((mask >> site) & 1ull) << s;
    }
    float val = G[lane * NPAT + pat];

#pragma unroll
    for (int off = 32; off > 0; off >>= 1)
        val += __shfl_down(val, off, 64);
    if (lane == 0) out[b] = val;
}

extern "C" void kernel_launch(void* const* d_in, const int* in_sizes, int n_in,
                              void* d_out, int out_size, void* d_ws, size_t ws_size,
                              hipStream_t stream) {
    const int*   inputs = (const int*)d_in[0];    // (BATCH, L) int32
    const int*   plq    = (const int*)d_in[1];    // (NP, 9) int32
    const float* eps    = (const float*)d_in[2];  // (2, NP, M, 9) fp32
    float* out = (float*)d_out;                   // (BATCH,) fp32
    float* G   = (float*)d_ws;                    // NP*NPAT floats = 128 KB

    build_table<<<NP * 4, 128, 0, stream>>>(eps, G);
    eval_kernel<<<BATCH / 4, 256, 0, stream>>>(inputs, plq, G, out);
}